// Round 8
// baseline (102.189 us; speedup 1.0000x reference)
//
#include <hip/hip_runtime.h>

// PointWarping: B=2, C=3, N=8192. Brute-force K=3 NN + inverse-distance flow interp.
// Round 8: Q=8 queries per wave (block's 4 waves share 8 queries, candidates
// split 4-way) -> wave-loads halve; 4 candidates in flight per scan iteration
// (4 independent dwordx4) -> 2x deeper MLP. Structure otherwise = round 7:
// pre-kernel writes warped points (x1+f1) as float4 into d_ws (L2-resident);
// queries wave-uniform in SGPRs; exact direct-form packed keys
// (25-bit d | 7-bit row); keys-only butterfly; ballot index recovery;
// exact epilogue recompute.

#define NPTS    8192
#define BLOCK   256
#define Q       8                 // queries per wave (wave-uniform, shared by block)
#define QPB     8                 // queries per block
#define QUARTER 2048              // candidates per wave (4-way split)
#define KMASK   0xFFFFFF80
#define EPSV    1e-10f

__device__ __forceinline__ float rfl_f32(float x) {
    // readfirstlane is b32: bit-cast, never numeric-convert
    return __int_as_float(__builtin_amdgcn_readfirstlane(__float_as_int(x)));
}

// sorted top-3 stream insert, keys only (3 VALU)
__device__ __forceinline__ void ksort3(float k, float& m0, float& m1, float& m2) {
    m2 = __builtin_amdgcn_fmed3f(k, m1, m2);
    m1 = __builtin_amdgcn_fmed3f(k, m0, m1);
    m0 = fminf(k, m0);
}

// sorted top-3 insert with index tracking (epilogue only)
__device__ __forceinline__ void insert3_idx(float k, int idx,
                                            float& m0, float& m1, float& m2,
                                            int& j0, int& j1, int& j2) {
    const bool c0 = k < m0;
    const bool c1 = k < m1;
    const bool c2 = k < m2;
    ksort3(k, m0, m1, m2);
    j2 = c1 ? j1 : (c2 ? idx : j2);
    j1 = c0 ? j0 : (c1 ? idx : j1);
    j0 = c0 ? idx : j0;
}

// pre-kernel: ws[b*NPTS+n] = float4(x1+f1, 0)
__global__ __launch_bounds__(256)
void warp_points_kernel(const float* __restrict__ xyz1,
                        const float* __restrict__ flow1,
                        float4* __restrict__ ws, int total) {
    const int i = blockIdx.x * 256 + threadIdx.x;
    if (i >= total) return;
    const int b = i / NPTS, n = i - b * NPTS;
    const float* x1 = xyz1 + (size_t)b * 3 * NPTS;
    const float* f1 = flow1 + (size_t)b * 3 * NPTS;
    const float px = x1[0*NPTS + n] + f1[0*NPTS + n];
    const float py = x1[1*NPTS + n] + f1[1*NPTS + n];
    const float pz = x1[2*NPTS + n] + f1[2*NPTS + n];
    ws[i] = make_float4(px, py, pz, 0.0f);
}

__global__ __launch_bounds__(BLOCK, 8)
void pointwarp_kernel(const float4* __restrict__ wsp,
                      const float* __restrict__ xyz2,
                      const float* __restrict__ flow1,
                      float* __restrict__ out) {
    __shared__ float s_k[4][Q][3];
    __shared__ int   s_i[4][Q][3];

    const int tid  = threadIdx.x;
    const int w    = tid >> 6;              // wave = candidate quarter [0,4)
    const int t    = tid & 63;              // lane
    const int blocksPerB = NPTS / QPB;      // 1024
    const int b     = blockIdx.x / blocksPerB;
    const int qblk  = (blockIdx.x % blocksPerB) * QPB;

    const float4* cand = wsp + (size_t)b * NPTS;
    const float*  x2   = xyz2 + (size_t)b * 3 * NPTS;
    const float*  f1   = flow1 + (size_t)b * 3 * NPTS;

    // wave-uniform queries -> SGPRs (bit-cast broadcast); all waves share them
    float qx[Q], qy[Q], qz[Q], k0[Q], k1[Q], k2[Q];
    #pragma unroll
    for (int i = 0; i < Q; ++i) {
        qx[i] = rfl_f32(x2[0*NPTS + qblk + i]);
        qy[i] = rfl_f32(x2[1*NPTS + qblk + i]);
        qz[i] = rfl_f32(x2[2*NPTS + qblk + i]);
        k0[i] = k1[i] = k2[i] = 3e38f;
    }

    // scan this wave's quarter: 4 candidates per iteration, 4 loads in flight
    const float4* base = cand + w * QUARTER + t;
    const int rowbase = w * (QUARTER / 64);   // global row = cand_idx >> 6, [0,128)
    for (int j = 0; j < QUARTER / 256; ++j) { // 8 iterations
        const float4 p0 = base[j * 256];
        const float4 p1 = base[j * 256 + 64];
        const float4 p2 = base[j * 256 + 128];
        const float4 p3 = base[j * 256 + 192];
        const int jg0 = rowbase + 4*j;
        #pragma unroll
        for (int i = 0; i < Q; ++i) {
            {
                const float dx = p0.x - qx[i], dy = p0.y - qy[i], dz = p0.z - qz[i];
                const float d  = fmaf(dx, dx, fmaf(dy, dy, dz*dz));
                ksort3(__int_as_float((__float_as_int(d) & KMASK) | jg0),
                       k0[i], k1[i], k2[i]);
            }
            {
                const float dx = p1.x - qx[i], dy = p1.y - qy[i], dz = p1.z - qz[i];
                const float d  = fmaf(dx, dx, fmaf(dy, dy, dz*dz));
                ksort3(__int_as_float((__float_as_int(d) & KMASK) | (jg0+1)),
                       k0[i], k1[i], k2[i]);
            }
            {
                const float dx = p2.x - qx[i], dy = p2.y - qy[i], dz = p2.z - qz[i];
                const float d  = fmaf(dx, dx, fmaf(dy, dy, dz*dz));
                ksort3(__int_as_float((__float_as_int(d) & KMASK) | (jg0+2)),
                       k0[i], k1[i], k2[i]);
            }
            {
                const float dx = p3.x - qx[i], dy = p3.y - qy[i], dz = p3.z - qz[i];
                const float d  = fmaf(dx, dx, fmaf(dy, dy, dz*dz));
                ksort3(__int_as_float((__float_as_int(d) & KMASK) | (jg0+3)),
                       k0[i], k1[i], k2[i]);
            }
        }
    }

    // save pre-merge per-lane top-3 keys (for index resolution)
    float a0[Q], a1[Q], a2[Q];
    #pragma unroll
    for (int i = 0; i < Q; ++i) { a0[i] = k0[i]; a1[i] = k1[i]; a2[i] = k2[i]; }

    // keys-only butterfly merge: 64 partial top-3 -> wave top-3 (all lanes)
    #pragma unroll
    for (int step = 1; step < 64; step <<= 1) {
        #pragma unroll
        for (int i = 0; i < Q; ++i) {
            const float b0 = __shfl_xor(k0[i], step, 64);
            const float b1 = __shfl_xor(k1[i], step, 64);
            const float b2 = __shfl_xor(k2[i], step, 64);
            ksort3(b0, k0[i], k1[i], k2[i]);
            ksort3(b1, k0[i], k1[i], k2[i]);
            ksort3(b2, k0[i], k1[i], k2[i]);
        }
    }

    // resolve indices: first lane whose pre-merge top-3 contains the final key
    int i0[Q], i1[Q], i2[Q];
    #pragma unroll
    for (int i = 0; i < Q; ++i) {
        {
            const float kf = k0[i];
            const unsigned long long m = __ballot(kf == a0[i] || kf == a1[i] || kf == a2[i]);
            i0[i] = ((__float_as_int(kf) & 0x7F) << 6) | (__ffsll(m) - 1);
        }
        {
            const float kf = k1[i];
            const unsigned long long m = __ballot(kf == a0[i] || kf == a1[i] || kf == a2[i]);
            i1[i] = ((__float_as_int(kf) & 0x7F) << 6) | (__ffsll(m) - 1);
        }
        {
            const float kf = k2[i];
            const unsigned long long m = __ballot(kf == a0[i] || kf == a1[i] || kf == a2[i]);
            i2[i] = ((__float_as_int(kf) & 0x7F) << 6) | (__ffsll(m) - 1);
        }
    }

    // publish wave results (all lanes identical; lane i<Q writes query i)
    #pragma unroll
    for (int i = 0; i < Q; ++i) {
        if (t == i) {
            s_k[w][i][0] = k0[i]; s_i[w][i][0] = i0[i];
            s_k[w][i][1] = k1[i]; s_i[w][i][1] = i1[i];
            s_k[w][i][2] = k2[i]; s_i[w][i][2] = i2[i];
        }
    }
    __syncthreads();

    // one thread per query: merge the four quarters, exact weights, write
    if (tid < QPB) {
        const int qi = tid;
        float m0 = 3e38f, m1 = 3e38f, m2 = 3e38f;
        int   j0 = 0, j1 = 0, j2 = 0;
        #pragma unroll
        for (int wv = 0; wv < 4; ++wv) {
            #pragma unroll
            for (int s = 0; s < 3; ++s) {
                insert3_idx(s_k[wv][qi][s], s_i[wv][qi][s],
                            m0, m1, m2, j0, j1, j2);
            }
        }
        const int n2 = qblk + qi;
        const float gx = x2[0*NPTS + n2];
        const float gy = x2[1*NPTS + n2];
        const float gz = x2[2*NPTS + n2];
        float dd[3];
        const int js[3] = {j0, j1, j2};
        #pragma unroll
        for (int s = 0; s < 3; ++s) {
            const float4 p = cand[js[s]];
            const float dx = p.x - gx, dy = p.y - gy, dz = p.z - gz;
            dd[s] = fmaf(dx, dx, fmaf(dy, dy, dz*dz));
        }
        float w0 = 1.0f / fmaxf(sqrtf(dd[0]), EPSV);
        float w1 = 1.0f / fmaxf(sqrtf(dd[1]), EPSV);
        float w2v = 1.0f / fmaxf(sqrtf(dd[2]), EPSV);
        const float ws = w0 + w1 + w2v;
        w0 /= ws; w1 /= ws; w2v /= ws;

        float* o = out + (size_t)b * 3 * NPTS;
        #pragma unroll
        for (int c = 0; c < 3; ++c) {
            const float fl = w0  * f1[c*NPTS + j0]
                           + w1  * f1[c*NPTS + j1]
                           + w2v * f1[c*NPTS + j2];
            o[c*NPTS + n2] = x2[c*NPTS + n2] - fl;
        }
    }
}

extern "C" void kernel_launch(void* const* d_in, const int* in_sizes, int n_in,
                              void* d_out, int out_size, void* d_ws, size_t ws_size,
                              hipStream_t stream) {
    const float* xyz1  = (const float*)d_in[0];
    const float* xyz2  = (const float*)d_in[1];
    const float* flow1 = (const float*)d_in[2];
    float* out = (float*)d_out;
    float4* ws = (float4*)d_ws;

    const int B = in_sizes[0] / (3 * NPTS);       // = 2
    const int total = B * NPTS;
    warp_points_kernel<<<(total + 255) / 256, 256, 0, stream>>>(xyz1, flow1, ws, total);
    const int grid = B * (NPTS / QPB);            // 2048 blocks = 8 per CU
    pointwarp_kernel<<<grid, BLOCK, 0, stream>>>(ws, xyz2, flow1, out);
}